// Round 7
// baseline (311.839 us; speedup 1.0000x reference)
//
#include <hip/hip_runtime.h>
#include <hip/hip_bf16.h>
#include <stdint.h>

#define BB 8
#define NN 2048
#define MM 2048
#define CC 256

typedef __attribute__((ext_vector_type(8))) short short8;
typedef __attribute__((ext_vector_type(4))) float f32x4;

__device__ __forceinline__ void gl_lds16(const void* g, void* l) {
    __builtin_amdgcn_global_load_lds(
        (const __attribute__((address_space(1))) void*)g,
        (__attribute__((address_space(3))) void*)l, 16, 0, 0);
}

__device__ __forceinline__ unsigned short f2bf(float f) {
    __hip_bfloat16 h = __float2bfloat16(f);
    return *reinterpret_cast<unsigned short*>(&h);
}

// ---------------- normalize + cast + layout pre-pass (+acc zeroing) ----------------
// One wave per row of C=256 floats.
// A layout (bytes):  row*512 + c*64 + kbL*16 + (lane&1)*8,  kbL = kb ^ ((row>>1)&3)
//   -> linear global_load_lds staging + swizzled ds_read (0 conflicts, proven).
// B layout (bytes):  batch*1MiB + ((r>>4)*8 + c)*1024 + kbL*256 + (r&15)*16 + ...
//   -> each wave MFMA B-fragment load is a bijective permutation of a
//      contiguous 1 KiB block => fully coalesced register loads.
__global__ __launch_bounds__(256) void norm_cast_kernel(
    const float* __restrict__ x1, const float* __restrict__ x2,
    char* __restrict__ outA, char* __restrict__ outB,
    float* __restrict__ lsum, unsigned int* __restrict__ vcnt,
    unsigned int* __restrict__ flags, unsigned int* __restrict__ done) {
    if (blockIdx.x == 0 && threadIdx.x < 8) {
        int t = threadIdx.x;
        lsum[t] = 0.0f; vcnt[t] = 0u; flags[t] = 0u; flags[BB + t] = 0u;
        if (t == 0) *done = 0u;
    }
    int gwave = (blockIdx.x * blockDim.x + threadIdx.x) >> 6;
    int lane  = threadIdx.x & 63;
    bool isA = gwave < BB * NN;
    const float* src = isA ? x1 : x2;
    int row = isA ? gwave : gwave - BB * NN;
    float4 v = reinterpret_cast<const float4*>(src + (size_t)row * CC)[lane];
    float ss = v.x * v.x + v.y * v.y + v.z * v.z + v.w * v.w;
#pragma unroll
    for (int off = 32; off; off >>= 1) ss += __shfl_xor(ss, off);
    float inv = 1.0f / fmaxf(sqrtf(ss), 1e-8f);
    ushort4 h;
    h.x = f2bf(v.x * inv); h.y = f2bf(v.y * inv);
    h.z = f2bf(v.z * inv); h.w = f2bf(v.w * inv);
    int c   = lane >> 3;              // k-chunk 0..7
    int kb  = (lane >> 1) & 3;        // logical 16B k-unit
    int kbL = kb ^ ((row >> 1) & 3);  // swizzled unit
    char* p;
    if (isA) {
        p = outA + (size_t)row * 512 + c * 64 + kbL * 16 + (lane & 1) * 8;
    } else {
        int b = row >> 11, r = row & 2047;
        p = outB + (size_t)b * 1048576 + (size_t)((r >> 4) * 8 + c) * 1024
                 + kbL * 256 + (r & 15) * 16 + (lane & 1) * 8;
    }
    *reinterpret_cast<ushort4*>(p) = h;
}

// ---------------- fused MFMA cos-sim + BCE reduce + finalize ----------------
// 1024 blocks = 4/CU (32 waves/CU), XCD-swizzled: b = blockIdx&7. Each block:
// 64-row A-panel full-K in LDS (32 KB, staged once), 4 m-tiles of 128 cols;
// B fragments + z labels stream to registers; fused epilogue; ticket finalize.
__global__ __launch_bounds__(512, 8) void fused_mfma_kernel(
    const int*  __restrict__ z,
    const char* __restrict__ nA, const char* __restrict__ nB,
    const float* __restrict__ tptr, const float* __restrict__ bptr,
    float* __restrict__ lsum, unsigned int* __restrict__ vcnt,
    unsigned int* __restrict__ flags, unsigned int* __restrict__ done,
    float* __restrict__ out) {

    __shared__ __align__(16) char ldsA[32768];   // 8 k-chunks x 64 rows x 64 B
    __shared__ float        s_sum[8];
    __shared__ unsigned int s_cnt[8];
    __shared__ unsigned int s_flag[2];

    const int flat = blockIdx.x;
    const int b    = flat & 7;           // XCD id == batch
    const int rest = flat >> 3;          // 0..127
    const int n0   = (rest & 31) * 64;   // 32 n-panels of 64 rows
    const int mq   = rest >> 5;          // 0..3 (m-quarter: 4 tiles of 128)
    const int tid  = threadIdx.x, lane = tid & 63, wid = tid >> 6;
    const int wr = wid >> 2, wc = wid & 3, l15 = lane & 15;
    const int q4  = (lane >> 4) << 2;
    const int kbL = (lane >> 4) ^ ((l15 >> 1) & 3);

    // ---- A staging: wave `wid` stages k-chunk c=wid, 64 rows (4 x 1 KiB) ----
    {
        const char* src = nA + ((size_t)b * NN + n0) * 512
                        + (size_t)(lane >> 2) * 512 + wid * 64 + (lane & 3) * 16;
        char* dst = ldsA + wid * 4096;
#pragma unroll
        for (int g = 0; g < 4; g++)
            gl_lds16(src + (size_t)g * 8192, dst + g * 1024);
    }

    const char* gB0 = nB + (size_t)b * 1048576 + (size_t)mq * 262144
                    + kbL * 256 + l15 * 16;
    const int* zb = z + ((size_t)b * NN + n0 + wr * 32 + q4) * MM
                      + mq * 512 + wc * 32 + l15;

    const float tv = *tptr;
    const float bs = *bptr;
    const float LOG2E = 1.4426950408889634f;
    const float LN2   = 0.6931471805599453f;

    __syncthreads();   // A-slab resident

    float lsu = 0.0f;
    int   lcnt = 0;
    int   mxz = -1, mnz = 1;

#pragma unroll
    for (int mt = 0; mt < 4; mt++) {
        const char* gBt = gB0 + mt * 65536;

        // B fragments: 16 x dwordx4, coalesced 1 KiB blocks (L2-resident)
        short8 bfr[8][2];
#pragma unroll
        for (int c = 0; c < 8; c++)
#pragma unroll
            for (int n = 0; n < 2; n++)
                bfr[c][n] = *reinterpret_cast<const short8*>(
                    gBt + (wc * 2 + n) * 8192 + c * 1024);

        // z labels: 16 dwords, issued early, consumed after the MFMA block
        int zr[16];
#pragma unroll
        for (int m = 0; m < 2; m++)
#pragma unroll
            for (int r = 0; r < 4; r++)
#pragma unroll
                for (int n = 0; n < 2; n++)
                    zr[(m * 4 + r) * 2 + n] = zb[mt * 128 + (m * 16 + r) * MM + n * 16];

        // MFMA over full K (wave-tile 32x32)
        f32x4 acc[2][2] = {};
#pragma unroll
        for (int c = 0; c < 8; c++) {
            short8 af[2];
#pragma unroll
            for (int m = 0; m < 2; m++)
                af[m] = *reinterpret_cast<const short8*>(
                    ldsA + c * 4096 + (wr * 32 + m * 16 + l15) * 64 + kbL * 16);
#pragma unroll
            for (int m = 0; m < 2; m++) {
                acc[m][0] = __builtin_amdgcn_mfma_f32_16x16x32_bf16(af[m], bfr[c][0], acc[m][0], 0, 0, 0);
                acc[m][1] = __builtin_amdgcn_mfma_f32_16x16x32_bf16(af[m], bfr[c][1], acc[m][1], 0, 0, 0);
            }
        }

        // fused epilogue (exp2-domain log-sigmoid; v_exp_f32 = 2^x, v_log_f32 = log2 x)
#pragma unroll
        for (int m = 0; m < 2; m++)
#pragma unroll
            for (int r = 0; r < 4; r++)
#pragma unroll
                for (int n = 0; n < 2; n++) {
                    int zij = zr[(m * 4 + r) * 2 + n];
                    float cs = acc[m][n][r];
                    float p  = fmaf(tv, cs, -bs);
                    float y  = (zij < 0) ? -p : p;
                    float e  = __builtin_amdgcn_exp2f(-fabsf(y) * LOG2E);
                    float lg = __builtin_amdgcn_logf(1.0f + e);
                    float ls = fminf(y, 0.0f) - LN2 * lg;
                    if (zij != 0) { lsu += ls; lcnt++; }
                    mxz = max(mxz, zij); mnz = min(mnz, zij);
                }
    }

    // ---------------- block reduction ----------------
#pragma unroll
    for (int off = 32; off; off >>= 1) {
        lsu  += __shfl_down(lsu, off);
        lcnt += __shfl_down(lcnt, off);
    }
    unsigned long long mp = __ballot(mxz > 0);
    unsigned long long mn = __ballot(mnz < 0);

    __syncthreads();
    if (tid < 2) s_flag[tid] = 0u;
    __syncthreads();
    if (lane == 0) {
        s_sum[wid] = lsu;
        s_cnt[wid] = (unsigned int)lcnt;
        if (mp) atomicOr(&s_flag[0], 1u);
        if (mn) atomicOr(&s_flag[1], 1u);
    }
    __syncthreads();
    if (tid == 0) {
        float ts = 0.f; unsigned int tc = 0u;
#pragma unroll
        for (int w = 0; w < 8; w++) { ts += s_sum[w]; tc += s_cnt[w]; }
        atomicAdd(&lsum[b], ts);
        atomicAdd(&vcnt[b], tc);
        if (s_flag[0]) atomicOr(&flags[b], 1u);
        if (s_flag[1]) atomicOr(&flags[BB + b], 1u);
        __threadfence();
        unsigned int old = atomicAdd(done, 1u);
        if (old == gridDim.x - 1) {
            // last block: finalize (device-scope atomic reads for coherence)
            __threadfence();
            double s = 0.0, c = 0.0;
#pragma unroll
            for (int bb = 0; bb < BB; bb++) {
                unsigned int fp = atomicOr(&flags[bb], 0u);
                unsigned int fn = atomicOr(&flags[BB + bb], 0u);
                float        sv = atomicAdd(&lsum[bb], 0.0f);
                unsigned int cv = atomicAdd(&vcnt[bb], 0u);
                if (fp && fn) { s += (double)sv; c += (double)cv; }
            }
            out[0] = (float)(-s / c);
        }
    }
}

extern "C" void kernel_launch(void* const* d_in, const int* in_sizes, int n_in,
                              void* d_out, int out_size, void* d_ws, size_t ws_size,
                              hipStream_t stream) {
    const int*   z   = (const int*)  d_in[0];
    const float* x1  = (const float*)d_in[1];
    const float* x2  = (const float*)d_in[2];
    const float* tp  = (const float*)d_in[3];
    const float* bp  = (const float*)d_in[4];
    float* out = (float*)d_out;

    char* ws = (char*)d_ws;
    char*  normA = ws;                                  // 8 MiB
    char*  normB = ws + (size_t)BB * NN * 512;          // 8 MiB
    char*  accb  = ws + (size_t)BB * (NN + MM) * 512;
    float*        lsum  = (float*)accb;
    unsigned int* vcnt  = (unsigned int*)(accb + 64);
    unsigned int* flags = (unsigned int*)(accb + 128);
    unsigned int* done  = (unsigned int*)(accb + 256);

    hipLaunchKernelGGL(norm_cast_kernel, dim3(BB * (NN + MM) / 4), dim3(256), 0, stream,
                       x1, x2, normA, normB, lsum, vcnt, flags, done);

    hipLaunchKernelGGL(fused_mfma_kernel, dim3(1024), dim3(512), 0, stream,
                       z, normA, normB, tp, bp, lsum, vcnt, flags, done, out);
}

// Round 8
// 304.842 us; speedup vs baseline: 1.0230x; 1.0230x over previous
//
#include <hip/hip_runtime.h>
#include <hip/hip_bf16.h>
#include <stdint.h>

#define BB 8
#define NN 2048
#define MM 2048
#define CC 256

typedef __attribute__((ext_vector_type(8))) short short8;
typedef __attribute__((ext_vector_type(4))) float f32x4;

__device__ __forceinline__ void gl_lds16(const void* g, void* l) {
    __builtin_amdgcn_global_load_lds(
        (const __attribute__((address_space(1))) void*)g,
        (__attribute__((address_space(3))) void*)l, 16, 0, 0);
}

__device__ __forceinline__ unsigned short f2bf(float f) {
    __hip_bfloat16 h = __float2bfloat16(f);
    return *reinterpret_cast<unsigned short*>(&h);
}

// ---------------- normalize + cast + layout pre-pass (+acc zeroing) ----------------
// One wave per row of C=256 floats.
// A layout (bytes):  row*512 + c*64 + kbL*16 + (lane&1)*8,  kbL = kb ^ ((row>>1)&3)
//   -> linear global_load_lds staging + swizzled ds_read (0 conflicts, proven).
// B layout (bytes):  batch*1MiB + ((r>>4)*8 + c)*1024 + kbL*256 + (r&15)*16 + ...
//   -> each wave MFMA B-fragment load is a bijective permutation of a
//      contiguous 1 KiB block => fully coalesced register loads.
__global__ __launch_bounds__(256) void norm_cast_kernel(
    const float* __restrict__ x1, const float* __restrict__ x2,
    char* __restrict__ outA, char* __restrict__ outB,
    float* __restrict__ lsum, unsigned int* __restrict__ vcnt,
    unsigned int* __restrict__ flags, unsigned int* __restrict__ done) {
    if (blockIdx.x == 0 && threadIdx.x < 8) {
        int t = threadIdx.x;
        lsum[t] = 0.0f; vcnt[t] = 0u; flags[t] = 0u; flags[BB + t] = 0u;
        if (t == 0) *done = 0u;
    }
    int gwave = (blockIdx.x * blockDim.x + threadIdx.x) >> 6;
    int lane  = threadIdx.x & 63;
    bool isA = gwave < BB * NN;
    const float* src = isA ? x1 : x2;
    int row = isA ? gwave : gwave - BB * NN;
    float4 v = reinterpret_cast<const float4*>(src + (size_t)row * CC)[lane];
    float ss = v.x * v.x + v.y * v.y + v.z * v.z + v.w * v.w;
#pragma unroll
    for (int off = 32; off; off >>= 1) ss += __shfl_xor(ss, off);
    float inv = 1.0f / fmaxf(sqrtf(ss), 1e-8f);
    ushort4 h;
    h.x = f2bf(v.x * inv); h.y = f2bf(v.y * inv);
    h.z = f2bf(v.z * inv); h.w = f2bf(v.w * inv);
    int c   = lane >> 3;              // k-chunk 0..7
    int kb  = (lane >> 1) & 3;        // logical 16B k-unit
    int kbL = kb ^ ((row >> 1) & 3);  // swizzled unit
    char* p;
    if (isA) {
        p = outA + (size_t)row * 512 + c * 64 + kbL * 16 + (lane & 1) * 8;
    } else {
        int b = row >> 11, r = row & 2047;
        p = outB + (size_t)b * 1048576 + (size_t)((r >> 4) * 8 + c) * 1024
                 + kbL * 256 + (r & 15) * 16 + (lane & 1) * 8;
    }
    *reinterpret_cast<ushort4*>(p) = h;
}

// ---------------- fused MFMA cos-sim + BCE reduce + finalize ----------------
// 1024 blocks, launch_bounds(512,6): 3 blocks/CU = 24 waves/CU, 85-VGPR cap
// (live set ~74 — no spill). XCD-swizzled b = blockIdx&7. Per block: 64-row
// A-panel full-K in LDS (32 KB, staged once); 4 m-tiles of 128; B fragments
// software-pipelined 2 chunks ahead of the MFMA chain; z issued after B0/B1
// (younger in vm queue -> first MFMA's wait doesn't drain it), consumed at
// the fused epilogue; grid-ticket finalize.
__global__ __launch_bounds__(512, 6) void fused_mfma_kernel(
    const int*  __restrict__ z,
    const char* __restrict__ nA, const char* __restrict__ nB,
    const float* __restrict__ tptr, const float* __restrict__ bptr,
    float* __restrict__ lsum, unsigned int* __restrict__ vcnt,
    unsigned int* __restrict__ flags, unsigned int* __restrict__ done,
    float* __restrict__ out) {

    __shared__ __align__(16) char ldsA[32768];   // 8 k-chunks x 64 rows x 64 B
    __shared__ float        s_sum[8];
    __shared__ unsigned int s_cnt[8];
    __shared__ unsigned int s_flag[2];

    const int flat = blockIdx.x;
    const int b    = flat & 7;           // XCD id == batch
    const int rest = flat >> 3;          // 0..127
    const int n0   = (rest & 31) * 64;   // 32 n-panels of 64 rows
    const int mq   = rest >> 5;          // 0..3 (m-quarter: 4 tiles of 128)
    const int tid  = threadIdx.x, lane = tid & 63, wid = tid >> 6;
    const int wr = wid >> 2, wc = wid & 3, l15 = lane & 15;
    const int q4  = (lane >> 4) << 2;
    const int kbL = (lane >> 4) ^ ((l15 >> 1) & 3);

    // ---- A staging: wave `wid` stages k-chunk c=wid, 64 rows (4 x 1 KiB) ----
    {
        const char* src = nA + ((size_t)b * NN + n0) * 512
                        + (size_t)(lane >> 2) * 512 + wid * 64 + (lane & 3) * 16;
        char* dst = ldsA + wid * 4096;
#pragma unroll
        for (int g = 0; g < 4; g++)
            gl_lds16(src + (size_t)g * 8192, dst + g * 1024);
    }

    const char* gB0 = nB + (size_t)b * 1048576 + (size_t)mq * 262144
                    + kbL * 256 + l15 * 16;
    const int* zb = z + ((size_t)b * NN + n0 + wr * 32 + q4) * MM
                      + mq * 512 + wc * 32 + l15;

    const float tv = *tptr;
    const float bs = *bptr;
    const float LOG2E = 1.4426950408889634f;
    const float LN2   = 0.6931471805599453f;

    __syncthreads();   // A-slab resident

    float lsu = 0.0f;
    int   lcnt = 0;
    int   mxz = -1, mnz = 1;

#pragma unroll
    for (int mt = 0; mt < 4; mt++) {
        const char* gBt = gB0 + mt * 65536;

        short8 bfr[8][2];          // static-indexed only; ~2-3 chunks live at once
        int    zr[16];
        f32x4  acc[2][2] = {};

#define ISSUE(c)                                                                  \
        do {                                                                      \
            bfr[c][0] = *reinterpret_cast<const short8*>(gBt + (wc * 2 + 0) * 8192 + (c) * 1024); \
            bfr[c][1] = *reinterpret_cast<const short8*>(gBt + (wc * 2 + 1) * 8192 + (c) * 1024); \
        } while (0)

#define MF(c)                                                                     \
        do {                                                                      \
            short8 af0 = *reinterpret_cast<const short8*>(                        \
                ldsA + (c) * 4096 + (wr * 32 + 0 * 16 + l15) * 64 + kbL * 16);    \
            short8 af1 = *reinterpret_cast<const short8*>(                        \
                ldsA + (c) * 4096 + (wr * 32 + 1 * 16 + l15) * 64 + kbL * 16);    \
            acc[0][0] = __builtin_amdgcn_mfma_f32_16x16x32_bf16(af0, bfr[c][0], acc[0][0], 0, 0, 0); \
            acc[0][1] = __builtin_amdgcn_mfma_f32_16x16x32_bf16(af0, bfr[c][1], acc[0][1], 0, 0, 0); \
            acc[1][0] = __builtin_amdgcn_mfma_f32_16x16x32_bf16(af1, bfr[c][0], acc[1][0], 0, 0, 0); \
            acc[1][1] = __builtin_amdgcn_mfma_f32_16x16x32_bf16(af1, bfr[c][1], acc[1][1], 0, 0, 0); \
        } while (0)

        ISSUE(0); ISSUE(1);
        // z labels issued AFTER B0/B1: younger in the vm queue, so MFMA's
        // waits for B never drain them; they land under the MFMA phase.
#pragma unroll
        for (int m = 0; m < 2; m++)
#pragma unroll
            for (int r = 0; r < 4; r++)
#pragma unroll
                for (int n = 0; n < 2; n++)
                    zr[(m * 4 + r) * 2 + n] = zb[mt * 128 + (m * 16 + r) * MM + n * 16];

        ISSUE(2);
        MF(0); ISSUE(3);
        MF(1); ISSUE(4);
        MF(2); ISSUE(5);
        MF(3); ISSUE(6);
        MF(4); ISSUE(7);
        MF(5);
        MF(6);
        MF(7);
#undef ISSUE
#undef MF

        // fused epilogue (exp2-domain log-sigmoid; v_exp_f32 = 2^x, v_log_f32 = log2 x)
#pragma unroll
        for (int m = 0; m < 2; m++)
#pragma unroll
            for (int r = 0; r < 4; r++)
#pragma unroll
                for (int n = 0; n < 2; n++) {
                    int zij = zr[(m * 4 + r) * 2 + n];
                    float cs = acc[m][n][r];
                    float p  = fmaf(tv, cs, -bs);
                    float y  = (zij < 0) ? -p : p;
                    float e  = __builtin_amdgcn_exp2f(-fabsf(y) * LOG2E);
                    float lg = __builtin_amdgcn_logf(1.0f + e);
                    float ls = fminf(y, 0.0f) - LN2 * lg;
                    if (zij != 0) { lsu += ls; lcnt++; }
                    mxz = max(mxz, zij); mnz = min(mnz, zij);
                }
    }

    // ---------------- block reduction ----------------
#pragma unroll
    for (int off = 32; off; off >>= 1) {
        lsu  += __shfl_down(lsu, off);
        lcnt += __shfl_down(lcnt, off);
    }
    unsigned long long mp = __ballot(mxz > 0);
    unsigned long long mn = __ballot(mnz < 0);

    __syncthreads();
    if (tid < 2) s_flag[tid] = 0u;
    __syncthreads();
    if (lane == 0) {
        s_sum[wid] = lsu;
        s_cnt[wid] = (unsigned int)lcnt;
        if (mp) atomicOr(&s_flag[0], 1u);
        if (mn) atomicOr(&s_flag[1], 1u);
    }
    __syncthreads();
    if (tid == 0) {
        float ts = 0.f; unsigned int tc = 0u;
#pragma unroll
        for (int w = 0; w < 8; w++) { ts += s_sum[w]; tc += s_cnt[w]; }
        atomicAdd(&lsum[b], ts);
        atomicAdd(&vcnt[b], tc);
        if (s_flag[0]) atomicOr(&flags[b], 1u);
        if (s_flag[1]) atomicOr(&flags[BB + b], 1u);
        __threadfence();
        unsigned int old = atomicAdd(done, 1u);
        if (old == gridDim.x - 1) {
            // last block: finalize (device-scope atomic reads for coherence)
            __threadfence();
            double s = 0.0, c = 0.0;
#pragma unroll
            for (int bb = 0; bb < BB; bb++) {
                unsigned int fp = atomicOr(&flags[bb], 0u);
                unsigned int fn = atomicOr(&flags[BB + bb], 0u);
                float        sv = atomicAdd(&lsum[bb], 0.0f);
                unsigned int cv = atomicAdd(&vcnt[bb], 0u);
                if (fp && fn) { s += (double)sv; c += (double)cv; }
            }
            out[0] = (float)(-s / c);
        }
    }
}

extern "C" void kernel_launch(void* const* d_in, const int* in_sizes, int n_in,
                              void* d_out, int out_size, void* d_ws, size_t ws_size,
                              hipStream_t stream) {
    const int*   z   = (const int*)  d_in[0];
    const float* x1  = (const float*)d_in[1];
    const float* x2  = (const float*)d_in[2];
    const float* tp  = (const float*)d_in[3];
    const float* bp  = (const float*)d_in[4];
    float* out = (float*)d_out;

    char* ws = (char*)d_ws;
    char*  normA = ws;                                  // 8 MiB
    char*  normB = ws + (size_t)BB * NN * 512;          // 8 MiB
    char*  accb  = ws + (size_t)BB * (NN + MM) * 512;
    float*        lsum  = (float*)accb;
    unsigned int* vcnt  = (unsigned int*)(accb + 64);
    unsigned int* flags = (unsigned int*)(accb + 128);
    unsigned int* done  = (unsigned int*)(accb + 256);

    hipLaunchKernelGGL(norm_cast_kernel, dim3(BB * (NN + MM) / 4), dim3(256), 0, stream,
                       x1, x2, normA, normB, lsum, vcnt, flags, done);

    hipLaunchKernelGGL(fused_mfma_kernel, dim3(1024), dim3(512), 0, stream,
                       z, normA, normB, tp, bp, lsum, vcnt, flags, done, out);
}

// Round 9
// 80.239 us; speedup vs baseline: 3.8864x; 3.7992x over previous
//
#include <hip/hip_runtime.h>
#include <hip/hip_bf16.h>
#include <stdint.h>

#define BB 8
#define NN 2048
#define MM 2048
#define CC 256

typedef __attribute__((ext_vector_type(8))) short short8;
typedef __attribute__((ext_vector_type(4))) float f32x4;

__device__ __forceinline__ void gl_lds16(const void* g, void* l) {
    __builtin_amdgcn_global_load_lds(
        (const __attribute__((address_space(1))) void*)g,
        (__attribute__((address_space(3))) void*)l, 16, 0, 0);
}

__device__ __forceinline__ unsigned short f2bf(float f) {
    __hip_bfloat16 h = __float2bfloat16(f);
    return *reinterpret_cast<unsigned short*>(&h);
}

// ---------------- normalize + cast + layout pre-pass (+acc zeroing) ----------------
// One wave per row of C=256 floats. Both outputs are laid out so that the fused
// kernel's LINEAR global_load_lds staging produces the swizzled LDS layout
// [chunk][row][kbL][16B] with kbL = kb ^ ((row>>1)&3) (0-conflict, proven R2-R5).
// A panel: 64 rows x 256k  -> 32 KB contiguous per (batch,rowblk).
// B half-tile: 128 cols x 128k -> 32 KB contiguous per (batch,colblk,kh).
__global__ __launch_bounds__(256) void norm_cast_kernel(
    const float* __restrict__ x1, const float* __restrict__ x2,
    char* __restrict__ outA, char* __restrict__ outB,
    float* __restrict__ lsum, unsigned int* __restrict__ vcnt,
    unsigned int* __restrict__ flags, unsigned int* __restrict__ done) {
    if (blockIdx.x == 0 && threadIdx.x < 8) {
        int t = threadIdx.x;
        lsum[t] = 0.0f; vcnt[t] = 0u; flags[t] = 0u; flags[BB + t] = 0u;
        if (t == 0) *done = 0u;
    }
    int gwave = (blockIdx.x * blockDim.x + threadIdx.x) >> 6;
    int lane  = threadIdx.x & 63;
    bool isA = gwave < BB * NN;
    const float* src = isA ? x1 : x2;
    int row = isA ? gwave : gwave - BB * NN;
    float4 v = reinterpret_cast<const float4*>(src + (size_t)row * CC)[lane];
    float ss = v.x * v.x + v.y * v.y + v.z * v.z + v.w * v.w;
#pragma unroll
    for (int off = 32; off; off >>= 1) ss += __shfl_xor(ss, off);
    float inv = 1.0f / fmaxf(sqrtf(ss), 1e-8f);
    ushort4 h;
    h.x = f2bf(v.x * inv); h.y = f2bf(v.y * inv);
    h.z = f2bf(v.z * inv); h.w = f2bf(v.w * inv);
    int c   = lane >> 3;              // k-chunk 0..7 (32 k each)
    int kb  = (lane >> 1) & 3;        // 16B k-unit within chunk
    int b   = row >> 11, r = row & 2047;
    int kbL = kb ^ ((r >> 1) & 3);    // bank swizzle
    char* p;
    if (isA) {
        // [b][rowblk 0..31][c 0..7][rlo 0..63][kbL][16B]
        p = outA + ((size_t)b << 20) + ((size_t)(r >> 6) << 15)
                 + (c << 12) + ((r & 63) << 6) + (kbL << 4) + ((lane & 1) << 3);
    } else {
        // [b][colblk 0..15][kh 0..1][g=c&3][clo 0..127][kbL][16B]
        p = outB + ((size_t)b << 20) + ((size_t)(r >> 7) << 16)
                 + ((c >> 2) << 15) + ((c & 3) << 13) + ((r & 127) << 6)
                 + (kbL << 4) + ((lane & 1) << 3);
    }
    *reinterpret_cast<ushort4*>(p) = h;
}

// ---------------- fused MFMA cos-sim + BCE reduce + finalize ----------------
// Grid 1024, 1 block/CU (98 KB LDS, launch_bounds(512,2): VGPR cap 256, no spill).
// b = blockIdx&7 (XCD == batch, panels L2-resident). Per block: 64-row A panel
// full-K in LDS + B 2x32KB half-tile dbuf staged by global_load_lds DMA with
// counted vmcnt (never 0 mid-loop). 8 phases = 4 m-tiles x 2 k-halves.
__global__ __launch_bounds__(512, 2) void fused_mfma_kernel(
    const int*  __restrict__ z,
    const char* __restrict__ nA, const char* __restrict__ nB,
    const float* __restrict__ tptr, const float* __restrict__ bptr,
    float* __restrict__ lsum, unsigned int* __restrict__ vcnt,
    unsigned int* __restrict__ flags, unsigned int* __restrict__ done,
    float* __restrict__ out) {

    __shared__ __align__(16) char ldsbuf[98304];   // A 32KB | B half-tile dbuf 2x32KB
    __shared__ float        s_sum[8];
    __shared__ unsigned int s_cnt[8];
    __shared__ unsigned int s_flag[2];
    char* ldsA = ldsbuf;
    char* ldsB = ldsbuf + 32768;

    const int flat = blockIdx.x;
    const int b    = flat & 7;
    const int rest = flat >> 3;          // 0..127
    const int n0   = (rest & 31) * 64;   // 32 n-panels of 64 rows
    const int mq   = rest >> 5;          // 0..3 (512-col quarter)
    const int tid  = threadIdx.x, lane = tid & 63, wid = tid >> 6;
    const int wr = wid >> 2, wc = wid & 3, l15 = lane & 15;
    const int kbA = (lane >> 4) ^ ((l15 >> 1) & 3);

    const float tv = *tptr;
    const float bs = *bptr;
    const float LOG2E = 1.4426950408889634f;
    const float LN2   = 0.6931471805599453f;

    // ---- issue A stage (4 DMA/thread, 32 KB total) ----
    {
        const char* sA = nA + ((size_t)b << 20) + ((size_t)(rest & 31) << 15);
        char* dA = ldsA + wid * 1024;
#pragma unroll
        for (int g = 0; g < 4; g++)
            gl_lds16(sA + (size_t)(g * 512 + tid) * 16, dA + g * 8192);
    }

#define STAGE_B(h)                                                                 \
    do {                                                                           \
        const char* sB = nB + ((size_t)b << 20) + ((size_t)(mq * 4 + ((h) >> 1)) << 16) \
                       + (((h) & 1) << 15);                                        \
        char* dB = ldsB + ((h) & 1) * 32768 + wid * 1024;                          \
        _Pragma("unroll")                                                          \
        for (int g = 0; g < 4; g++)                                                \
            gl_lds16(sB + (size_t)(g * 512 + tid) * 16, dB + g * 8192);            \
    } while (0)

    const int* zbase = z + ((size_t)b * NN + n0 + wr * 32 + ((lane >> 4) << 2)) * MM
                         + mq * 512 + wc * 32 + l15;
    int zr[16];
#define LOADZ(mt)                                                                  \
    do {                                                                           \
        _Pragma("unroll")                                                          \
        for (int mf = 0; mf < 2; mf++)                                             \
            _Pragma("unroll")                                                      \
            for (int rr = 0; rr < 4; rr++)                                         \
                _Pragma("unroll")                                                  \
                for (int nf = 0; nf < 2; nf++)                                     \
                    zr[(mf * 4 + rr) * 2 + nf] =                                   \
                        zbase[(size_t)(mf * 16 + rr) * MM + (mt) * 128 + nf * 16]; \
    } while (0)

    f32x4 acc[2][2];
#define ZACC()                                                                     \
    do {                                                                           \
        _Pragma("unroll")                                                          \
        for (int m = 0; m < 2; m++)                                                \
            _Pragma("unroll")                                                      \
            for (int n = 0; n < 2; n++) acc[m][n] = (f32x4){0.f, 0.f, 0.f, 0.f};   \
    } while (0)

#define COMPUTE(h)                                                                 \
    do {                                                                           \
        _Pragma("unroll")                                                          \
        for (int clo = 0; clo < 4; clo++) {                                        \
            const int cc = (((h) & 1) << 2) + clo;                                 \
            short8 af0 = *reinterpret_cast<const short8*>(                         \
                ldsA + cc * 4096 + (wr * 32 + l15) * 64 + kbA * 16);               \
            short8 af1 = *reinterpret_cast<const short8*>(                         \
                ldsA + cc * 4096 + (wr * 32 + 16 + l15) * 64 + kbA * 16);          \
            short8 bf0 = *reinterpret_cast<const short8*>(                         \
                ldsB + ((h) & 1) * 32768 + clo * 8192 + (wc * 32 + l15) * 64 + kbA * 16); \
            short8 bf1 = *reinterpret_cast<const short8*>(                         \
                ldsB + ((h) & 1) * 32768 + clo * 8192 + (wc * 32 + 16 + l15) * 64 + kbA * 16); \
            acc[0][0] = __builtin_amdgcn_mfma_f32_16x16x32_bf16(af0, bf0, acc[0][0], 0, 0, 0); \
            acc[0][1] = __builtin_amdgcn_mfma_f32_16x16x32_bf16(af0, bf1, acc[0][1], 0, 0, 0); \
            acc[1][0] = __builtin_amdgcn_mfma_f32_16x16x32_bf16(af1, bf0, acc[1][0], 0, 0, 0); \
            acc[1][1] = __builtin_amdgcn_mfma_f32_16x16x32_bf16(af1, bf1, acc[1][1], 0, 0, 0); \
        }                                                                          \
    } while (0)

    float lsu = 0.0f;
    int   lcnt = 0;
    int   mxz = -1, mnz = 1;
#define EPI(mt)                                                                    \
    do {                                                                           \
        _Pragma("unroll")                                                          \
        for (int mf = 0; mf < 2; mf++)                                             \
            _Pragma("unroll")                                                      \
            for (int rr = 0; rr < 4; rr++)                                         \
                _Pragma("unroll")                                                  \
                for (int nf = 0; nf < 2; nf++) {                                   \
                    int zij = zr[(mf * 4 + rr) * 2 + nf];                          \
                    float cs = acc[mf][nf][rr];                                    \
                    float pp = fmaf(tv, cs, -bs);                                  \
                    float y  = (zij < 0) ? -pp : pp;                               \
                    float e  = __builtin_amdgcn_exp2f(-fabsf(y) * LOG2E);          \
                    float lg = __builtin_amdgcn_logf(1.0f + e);                    \
                    float ls = fminf(y, 0.0f) - LN2 * lg;                          \
                    if (zij != 0) { lsu += ls; lcnt++; }                           \
                    mxz = max(mxz, zij); mnz = min(mnz, zij);                      \
                }                                                                  \
    } while (0)

#define FENCE() asm volatile("" ::: "memory")
#define BAR()   do { FENCE(); __builtin_amdgcn_s_barrier(); FENCE(); } while (0)
#define VMC(n)  asm volatile("s_waitcnt vmcnt(" #n ")" ::: "memory")

    // ---- prologue: A + B0 + B1 in flight, z(0) behind them ----
    STAGE_B(0);
    STAGE_B(1);
    FENCE();
    LOADZ(0);
    VMC(20);   // A(4)+B0(4) done; B1(4)+z0(16) still allowed outstanding
    BAR();

    ZACC(); COMPUTE(0);                               // h0 (tile0, k 0-127)
    BAR(); STAGE_B(2); VMC(20); BAR();                // wait B1; allow z0+B2
    COMPUTE(1); EPI(0);                               // h1 (tile0, k 128-255)
    BAR(); STAGE_B(3); VMC(4);  BAR();                // wait B2; allow B3
    ZACC(); LOADZ(1); COMPUTE(2);                     // h2 (tile1)
    BAR(); STAGE_B(4); VMC(20); BAR();                // wait B3; allow z1+B4
    COMPUTE(3); EPI(1);                               // h3
    BAR(); STAGE_B(5); VMC(4);  BAR();                // wait B4; allow B5
    ZACC(); LOADZ(2); COMPUTE(4);                     // h4 (tile2)
    BAR(); STAGE_B(6); VMC(20); BAR();                // wait B5; allow z2+B6
    COMPUTE(5); EPI(2);                               // h5
    BAR(); STAGE_B(7); VMC(4);  BAR();                // wait B6; allow B7
    ZACC(); LOADZ(3); COMPUTE(6);                     // h6 (tile3)
    BAR(); VMC(16); BAR();                            // wait B7; allow z3
    COMPUTE(7); EPI(3);                               // h7

#undef STAGE_B
#undef LOADZ
#undef ZACC
#undef COMPUTE
#undef EPI
#undef FENCE
#undef BAR
#undef VMC

    // ---------------- block reduction ----------------
#pragma unroll
    for (int off = 32; off; off >>= 1) {
        lsu  += __shfl_down(lsu, off);
        lcnt += __shfl_down(lcnt, off);
    }
    unsigned long long mp = __ballot(mxz > 0);
    unsigned long long mn = __ballot(mnz < 0);

    __syncthreads();
    if (tid < 2) s_flag[tid] = 0u;
    __syncthreads();
    if (lane == 0) {
        s_sum[wid] = lsu;
        s_cnt[wid] = (unsigned int)lcnt;
        if (mp) atomicOr(&s_flag[0], 1u);
        if (mn) atomicOr(&s_flag[1], 1u);
    }
    __syncthreads();
    if (tid == 0) {
        float ts = 0.f; unsigned int tc = 0u;
#pragma unroll
        for (int w = 0; w < 8; w++) { ts += s_sum[w]; tc += s_cnt[w]; }
        atomicAdd(&lsum[b], ts);
        atomicAdd(&vcnt[b], tc);
        if (s_flag[0]) atomicOr(&flags[b], 1u);
        if (s_flag[1]) atomicOr(&flags[BB + b], 1u);
        __threadfence();
        unsigned int old = atomicAdd(done, 1u);
        if (old == gridDim.x - 1) {
            __threadfence();
            double s = 0.0, c = 0.0;
#pragma unroll
            for (int bb = 0; bb < BB; bb++) {
                unsigned int fp = atomicOr(&flags[bb], 0u);
                unsigned int fn = atomicOr(&flags[BB + bb], 0u);
                float        sv = atomicAdd(&lsum[bb], 0.0f);
                unsigned int cv = atomicAdd(&vcnt[bb], 0u);
                if (fp && fn) { s += (double)sv; c += (double)cv; }
            }
            out[0] = (float)(-s / c);
        }
    }
}

extern "C" void kernel_launch(void* const* d_in, const int* in_sizes, int n_in,
                              void* d_out, int out_size, void* d_ws, size_t ws_size,
                              hipStream_t stream) {
    const int*   z   = (const int*)  d_in[0];
    const float* x1  = (const float*)d_in[1];
    const float* x2  = (const float*)d_in[2];
    const float* tp  = (const float*)d_in[3];
    const float* bp  = (const float*)d_in[4];
    float* out = (float*)d_out;

    char* ws = (char*)d_ws;
    char*  normA = ws;                                  // 8 MiB
    char*  normB = ws + (size_t)BB * NN * 512;          // 8 MiB
    char*  accb  = ws + (size_t)BB * (NN + MM) * 512;
    float*        lsum  = (float*)accb;
    unsigned int* vcnt  = (unsigned int*)(accb + 64);
    unsigned int* flags = (unsigned int*)(accb + 128);
    unsigned int* done  = (unsigned int*)(accb + 256);

    hipLaunchKernelGGL(norm_cast_kernel, dim3(BB * (NN + MM) / 4), dim3(256), 0, stream,
                       x1, x2, normA, normB, lsum, vcnt, flags, done);

    hipLaunchKernelGGL(fused_mfma_kernel, dim3(1024), dim3(512), 0, stream,
                       z, normA, normB, tp, bp, lsum, vcnt, flags, done, out);
}